// Round 6
// baseline (125.384 us; speedup 1.0000x reference)
//
#include <hip/hip_runtime.h>

#define TOL 1e-6f
#define EPSF 1e-12f

typedef float f32x4 __attribute__((ext_vector_type(4)));

__device__ __forceinline__ float frcp(float x)  { return __builtin_amdgcn_rcpf(x); }
__device__ __forceinline__ float frsq(float x)  { return __builtin_amdgcn_rsqf(x); }
__device__ __forceinline__ float fsqrt(float x) { return __builtin_amdgcn_sqrtf(x); }

__device__ __forceinline__ void nt_store4(float* p, float a, float b, float c, float d) {
    f32x4 v = {a, b, c, d};
    __builtin_nontemporal_store(v, (f32x4*)p);
}

// Closed form for the reference's 12 damped-Newton iterations: the sag surface
// x = C r^2/(1+sqrt(1-C^2 r^2)) is exactly the sphere (x-R)^2 + r^2 = R^2,
// R = 1/C; Newton converges to the near ray-sphere root to fp32 precision.
// t = c0/(sqrt(bb^2 - aa*c0) - bb)  (bb<0: cancellation-free).
// Normal direction = (px-R, py, pz) = positive multiple of the ref gradient.

__global__ __launch_bounds__(256) void sphere_trace_kernel(
    const float* __restrict__ P,
    const float* __restrict__ V,
    const float* __restrict__ tf,
    const float* __restrict__ diameter_p,
    const float* __restrict__ C_p,
    const float* __restrict__ anchors,
    const float* __restrict__ scale_p,
    const unsigned char* __restrict__ normalize_p,
    float* __restrict__ out,
    int n)
{
    // ---- uniform scalar setup ----
    const float diameter = diameter_p[0];
    const float C        = C_p[0];
    const float scale    = scale_p[0];
    const float half = 0.5f * diameter;

    float a0 = anchors[0] * half;
    float a1 = anchors[1] * half;
    float r2a0 = a0 * a0;
    float r2a1 = a1 * a1;
    float s0 = fsqrt(fmaxf(1.0f - C * C * r2a0, EPSF));
    float s1 = fsqrt(fmaxf(1.0f - C * C * r2a1, EPSF));
    float e0 = C * r2a0 * frcp(1.0f + s0);
    float e1 = C * r2a1 * frcp(1.0f + s1);

    float A[3][3], b[3];
    #pragma unroll
    for (int i = 0; i < 3; ++i) {
        #pragma unroll
        for (int j = 0; j < 3; ++j) A[i][j] = tf[i * 4 + j] * scale;
        b[i] = tf[i * 4 + 3] - scale * e0 * tf[i * 4 + 0];
    }

    float ia = A[0][0], ib = A[0][1], ic = A[0][2];
    float id = A[1][0], ie = A[1][1], ifv = A[1][2];
    float ig = A[2][0], ih = A[2][1], ii = A[2][2];
    float det = ia * (ie * ii - ifv * ih) - ib * (id * ii - ifv * ig) + ic * (id * ih - ie * ig);
    float idet = frcp(det);
    float Ai[3][3];
    Ai[0][0] = (ie * ii - ifv * ih) * idet;
    Ai[0][1] = (ic * ih - ib * ii) * idet;
    Ai[0][2] = (ib * ifv - ic * ie) * idet;
    Ai[1][0] = (ifv * ig - id * ii) * idet;
    Ai[1][1] = (ia * ii - ic * ig) * idet;
    Ai[1][2] = (ic * id - ia * ifv) * idet;
    Ai[2][0] = (id * ih - ie * ig) * idet;
    Ai[2][1] = (ib * ig - ia * ih) * idet;
    Ai[2][2] = (ia * ie - ib * id) * idet;

    const float R    = 1.0f / C;
    const float RR   = R * R;
    const float rlim = half + TOL;

    const int gid0   = blockIdx.x * blockDim.x + threadIdx.x;
    const int stride = gridDim.x * blockDim.x;

    // ---- the two 4x4 matrices (32 floats) ----
    if (gid0 < 32) {
        int k = gid0;
        int m = k & 15;
        int i = m >> 2, j = m & 3;
        float v;
        if (k < 16) {
            v = (j < 3) ? tf[i * 4 + j] * scale
                        : tf[i * 4 + 3] - scale * e0 * tf[i * 4 + 0];
            out[5 * n + m] = v;
        } else {
            v = (j < 3) ? tf[i * 4 + j]
                        : tf[i * 4 + 3] + scale * (e1 - e0) * tf[i * 4 + 0];
            out[5 * n + 16 + m] = v;
        }
    }

    const int ngroups8 = n >> 3;   // 8 points per thread

    const f32x4* __restrict__ P4 = (const f32x4*)P;
    const f32x4* __restrict__ V4 = (const f32x4*)V;

    for (int g = gid0; g < ngroups8; g += stride) {
        const int base = 6 * g;    // 8 pts = 24 floats = 6 float4
        // issue all 12 loads up front (max memory-level parallelism)
        f32x4 pv[6], vv[6];
        #pragma unroll
        for (int i = 0; i < 6; ++i) pv[i] = P4[base + i];
        #pragma unroll
        for (int i = 0; i < 6; ++i) vv[i] = V4[base + i];
        const float* fp = (const float*)pv;
        const float* fv = (const float*)vv;

        float tt[8], nx[8], ny[8], nz[8], vd[8];
        #pragma unroll
        for (int j = 0; j < 8; ++j) {
            float dx = fp[3 * j + 0] - b[0];
            float dy = fp[3 * j + 1] - b[1];
            float dz = fp[3 * j + 2] - b[2];
            float Wx = fv[3 * j + 0], Wy = fv[3 * j + 1], Wz = fv[3 * j + 2];
            float plx = Ai[0][0] * dx + Ai[0][1] * dy + Ai[0][2] * dz;
            float ply = Ai[1][0] * dx + Ai[1][1] * dy + Ai[1][2] * dz;
            float plz = Ai[2][0] * dx + Ai[2][1] * dy + Ai[2][2] * dz;
            float vlx = Ai[0][0] * Wx + Ai[0][1] * Wy + Ai[0][2] * Wz;
            float vly = Ai[1][0] * Wx + Ai[1][1] * Wy + Ai[1][2] * Wz;
            float vlz = Ai[2][0] * Wx + Ai[2][1] * Wy + Ai[2][2] * Wz;

            float mx = plx - R;
            float bb = mx * vlx + ply * vly + plz * vlz;
            float aa = vlx * vlx + vly * vly + vlz * vlz;
            float c0 = mx * mx + ply * ply + plz * plz - RR;
            float D  = fmaxf(bb * bb - aa * c0, 0.0f);
            float q  = fsqrt(D) - bb;
            float t  = c0 * frcp(q);
            tt[j] = t;

            float py = __fadd_rn(ply, __fmul_rn(t, vly));
            float pz = __fadd_rn(plz, __fmul_rn(t, vlz));
            float r2 = __fadd_rn(__fmul_rn(py, py), __fmul_rn(pz, pz));
            vd[j] = (sqrtf(r2) <= rlim) ? 1.0f : 0.0f;

            float nlx = fmaf(t, vlx, mx);
            float nwx = nlx * Ai[0][0] + py * Ai[1][0] + pz * Ai[2][0];
            float nwy = nlx * Ai[0][1] + py * Ai[1][1] + pz * Ai[2][1];
            float nwz = nlx * Ai[0][2] + py * Ai[1][2] + pz * Ai[2][2];
            float invn = frsq(fmaf(nwx, nwx, fmaf(nwy, nwy, nwz * nwz)));
            nx[j] = nwx * invn; ny[j] = nwy * invn; nz[j] = nwz * invn;
        }

        // streaming (non-temporal) stores: don't pollute L2/L3 with the
        // write-once output, keep inputs resident in Infinity Cache
        float* tp = out + 8 * g;
        nt_store4(tp + 0, tt[0], tt[1], tt[2], tt[3]);
        nt_store4(tp + 4, tt[4], tt[5], tt[6], tt[7]);

        float* np_ = out + n + 24 * g;
        nt_store4(np_ +  0, nx[0], ny[0], nz[0], nx[1]);
        nt_store4(np_ +  4, ny[1], nz[1], nx[2], ny[2]);
        nt_store4(np_ +  8, nz[2], nx[3], ny[3], nz[3]);
        nt_store4(np_ + 12, nx[4], ny[4], nz[4], nx[5]);
        nt_store4(np_ + 16, ny[5], nz[5], nx[6], ny[6]);
        nt_store4(np_ + 20, nz[6], nx[7], ny[7], nz[7]);

        float* vp = out + 4 * n + 8 * g;
        nt_store4(vp + 0, vd[0], vd[1], vd[2], vd[3]);
        nt_store4(vp + 4, vd[4], vd[5], vd[6], vd[7]);
    }

    // ---- scalar tail (n % 8) ----
    const int rem0 = ngroups8 << 3;
    for (int idx = rem0 + gid0; idx < n; idx += stride) {
        float dx = P[3 * idx + 0] - b[0], dy = P[3 * idx + 1] - b[1], dz = P[3 * idx + 2] - b[2];
        float Wx = V[3 * idx + 0], Wy = V[3 * idx + 1], Wz = V[3 * idx + 2];
        float plx = Ai[0][0] * dx + Ai[0][1] * dy + Ai[0][2] * dz;
        float ply = Ai[1][0] * dx + Ai[1][1] * dy + Ai[1][2] * dz;
        float plz = Ai[2][0] * dx + Ai[2][1] * dy + Ai[2][2] * dz;
        float vlx = Ai[0][0] * Wx + Ai[0][1] * Wy + Ai[0][2] * Wz;
        float vly = Ai[1][0] * Wx + Ai[1][1] * Wy + Ai[1][2] * Wz;
        float vlz = Ai[2][0] * Wx + Ai[2][1] * Wy + Ai[2][2] * Wz;
        float mx = plx - R;
        float bb = mx * vlx + ply * vly + plz * vlz;
        float aa = vlx * vlx + vly * vly + vlz * vlz;
        float c0 = mx * mx + ply * ply + plz * plz - RR;
        float D  = fmaxf(bb * bb - aa * c0, 0.0f);
        float q  = fsqrt(D) - bb;
        float t  = c0 * frcp(q);
        float py = __fadd_rn(ply, __fmul_rn(t, vly));
        float pz = __fadd_rn(plz, __fmul_rn(t, vlz));
        float r2 = __fadd_rn(__fmul_rn(py, py), __fmul_rn(pz, pz));
        float nlx = fmaf(t, vlx, mx);
        float nwx = nlx * Ai[0][0] + py * Ai[1][0] + pz * Ai[2][0];
        float nwy = nlx * Ai[0][1] + py * Ai[1][1] + pz * Ai[2][1];
        float nwz = nlx * Ai[0][2] + py * Ai[1][2] + pz * Ai[2][2];
        float invn = frsq(fmaf(nwx, nwx, fmaf(nwy, nwy, nwz * nwz)));
        out[idx] = t;
        out[n + 3 * idx + 0] = nwx * invn;
        out[n + 3 * idx + 1] = nwy * invn;
        out[n + 3 * idx + 2] = nwz * invn;
        out[4 * n + idx] = (sqrtf(r2) <= rlim) ? 1.0f : 0.0f;
    }
}

extern "C" void kernel_launch(void* const* d_in, const int* in_sizes, int n_in,
                              void* d_out, int out_size, void* d_ws, size_t ws_size,
                              hipStream_t stream) {
    const float* P  = (const float*)d_in[0];
    const float* V  = (const float*)d_in[1];
    const float* tf = (const float*)d_in[2];
    const float* diameter = (const float*)d_in[3];
    const float* C        = (const float*)d_in[4];
    const float* anchors  = (const float*)d_in[5];
    const float* scale    = (const float*)d_in[6];
    const unsigned char* normalize = (const unsigned char*)d_in[7];
    float* out = (float*)d_out;

    const int n = in_sizes[0] / 3;   // P is (N,3)

    const int block = 256;
    int blocks = ((n >> 3) + block - 1) / block;
    if (blocks > 4096) blocks = 4096;
    if (blocks < 1) blocks = 1;

    sphere_trace_kernel<<<blocks, block, 0, stream>>>(
        P, V, tf, diameter, C, anchors, scale, normalize, out, n);
}

// Round 7
// 40.519 us; speedup vs baseline: 3.0945x; 3.0945x over previous
//
#include <hip/hip_runtime.h>

#define TOL 1e-6f
#define EPSF 1e-12f

typedef float f32x4 __attribute__((ext_vector_type(4)));

__device__ __forceinline__ float frcp(float x)  { return __builtin_amdgcn_rcpf(x); }
__device__ __forceinline__ float frsq(float x)  { return __builtin_amdgcn_rsqf(x); }
__device__ __forceinline__ float fsqrt(float x) { return __builtin_amdgcn_sqrtf(x); }

// Closed form for the reference's 12 damped-Newton iterations: the sag surface
// x = C r^2/(1+sqrt(1-C^2 r^2)) is exactly the sphere (x-R)^2 + r^2 = R^2,
// R = 1/C; Newton converges to the near ray-sphere root to fp32 precision.
// t = c0/(sqrt(bb^2 - aa*c0) - bb)  (bb<0: cancellation-free).
// Normal direction = (px-R, py, pz) = positive multiple of the ref gradient.
// NOTE (R5 lesson): do NOT use nontemporal stores here — they bypass L2 write
// coalescing and amplified WRITE_SIZE 82->220 MB (125 us). Plain stores merge
// to full lines in L2.

__global__ __launch_bounds__(256) void sphere_trace_kernel(
    const float* __restrict__ P,
    const float* __restrict__ V,
    const float* __restrict__ tf,
    const float* __restrict__ diameter_p,
    const float* __restrict__ C_p,
    const float* __restrict__ anchors,
    const float* __restrict__ scale_p,
    const unsigned char* __restrict__ normalize_p,
    float* __restrict__ out,
    int n)
{
    // ---- uniform scalar setup ----
    const float diameter = diameter_p[0];
    const float C        = C_p[0];
    const float scale    = scale_p[0];
    const float half = 0.5f * diameter;

    float a0 = anchors[0] * half;
    float a1 = anchors[1] * half;
    float r2a0 = a0 * a0;
    float r2a1 = a1 * a1;
    float s0 = fsqrt(fmaxf(1.0f - C * C * r2a0, EPSF));
    float s1 = fsqrt(fmaxf(1.0f - C * C * r2a1, EPSF));
    float e0 = C * r2a0 * frcp(1.0f + s0);
    float e1 = C * r2a1 * frcp(1.0f + s1);

    float A[3][3], b[3];
    #pragma unroll
    for (int i = 0; i < 3; ++i) {
        #pragma unroll
        for (int j = 0; j < 3; ++j) A[i][j] = tf[i * 4 + j] * scale;
        b[i] = tf[i * 4 + 3] - scale * e0 * tf[i * 4 + 0];
    }

    float ia = A[0][0], ib = A[0][1], ic = A[0][2];
    float id = A[1][0], ie = A[1][1], ifv = A[1][2];
    float ig = A[2][0], ih = A[2][1], ii = A[2][2];
    float det = ia * (ie * ii - ifv * ih) - ib * (id * ii - ifv * ig) + ic * (id * ih - ie * ig);
    float idet = frcp(det);
    float Ai[3][3];
    Ai[0][0] = (ie * ii - ifv * ih) * idet;
    Ai[0][1] = (ic * ih - ib * ii) * idet;
    Ai[0][2] = (ib * ifv - ic * ie) * idet;
    Ai[1][0] = (ifv * ig - id * ii) * idet;
    Ai[1][1] = (ia * ii - ic * ig) * idet;
    Ai[1][2] = (ic * id - ia * ifv) * idet;
    Ai[2][0] = (id * ih - ie * ig) * idet;
    Ai[2][1] = (ib * ig - ia * ih) * idet;
    Ai[2][2] = (ia * ie - ib * id) * idet;

    const float R    = 1.0f / C;
    const float RR   = R * R;
    const float rlim = half + TOL;

    const int gid0   = blockIdx.x * blockDim.x + threadIdx.x;
    const int stride = gridDim.x * blockDim.x;

    // ---- the two 4x4 matrices (32 floats) ----
    if (gid0 < 32) {
        int k = gid0;
        int m = k & 15;
        int i = m >> 2, j = m & 3;
        float v;
        if (k < 16) {
            v = (j < 3) ? tf[i * 4 + j] * scale
                        : tf[i * 4 + 3] - scale * e0 * tf[i * 4 + 0];
            out[5 * n + m] = v;
        } else {
            v = (j < 3) ? tf[i * 4 + j]
                        : tf[i * 4 + 3] + scale * (e1 - e0) * tf[i * 4 + 0];
            out[5 * n + 16 + m] = v;
        }
    }

    const int ngroups8 = n >> 3;   // 8 points per thread

    const f32x4* __restrict__ P4 = (const f32x4*)P;
    const f32x4* __restrict__ V4 = (const f32x4*)V;

    for (int g = gid0; g < ngroups8; g += stride) {
        const int base = 6 * g;    // 8 pts = 24 floats = 6 float4
        // issue all 12 loads up front (max memory-level parallelism)
        f32x4 pv[6], vv[6];
        #pragma unroll
        for (int i = 0; i < 6; ++i) pv[i] = P4[base + i];
        #pragma unroll
        for (int i = 0; i < 6; ++i) vv[i] = V4[base + i];
        const float* fp = (const float*)pv;
        const float* fv = (const float*)vv;

        float tt[8], nx[8], ny[8], nz[8], vd[8];
        #pragma unroll
        for (int j = 0; j < 8; ++j) {
            float dx = fp[3 * j + 0] - b[0];
            float dy = fp[3 * j + 1] - b[1];
            float dz = fp[3 * j + 2] - b[2];
            float Wx = fv[3 * j + 0], Wy = fv[3 * j + 1], Wz = fv[3 * j + 2];
            float plx = Ai[0][0] * dx + Ai[0][1] * dy + Ai[0][2] * dz;
            float ply = Ai[1][0] * dx + Ai[1][1] * dy + Ai[1][2] * dz;
            float plz = Ai[2][0] * dx + Ai[2][1] * dy + Ai[2][2] * dz;
            float vlx = Ai[0][0] * Wx + Ai[0][1] * Wy + Ai[0][2] * Wz;
            float vly = Ai[1][0] * Wx + Ai[1][1] * Wy + Ai[1][2] * Wz;
            float vlz = Ai[2][0] * Wx + Ai[2][1] * Wy + Ai[2][2] * Wz;

            float mx = plx - R;
            float bb = mx * vlx + ply * vly + plz * vlz;
            float aa = vlx * vlx + vly * vly + vlz * vlz;
            float c0 = mx * mx + ply * ply + plz * plz - RR;
            float D  = fmaxf(bb * bb - aa * c0, 0.0f);
            float q  = fsqrt(D) - bb;
            float t  = c0 * frcp(q);
            tt[j] = t;

            float py = __fadd_rn(ply, __fmul_rn(t, vly));
            float pz = __fadd_rn(plz, __fmul_rn(t, vlz));
            float r2 = __fadd_rn(__fmul_rn(py, py), __fmul_rn(pz, pz));
            vd[j] = (sqrtf(r2) <= rlim) ? 1.0f : 0.0f;

            float nlx = fmaf(t, vlx, mx);
            float nwx = nlx * Ai[0][0] + py * Ai[1][0] + pz * Ai[2][0];
            float nwy = nlx * Ai[0][1] + py * Ai[1][1] + pz * Ai[2][1];
            float nwz = nlx * Ai[0][2] + py * Ai[1][2] + pz * Ai[2][2];
            float invn = frsq(fmaf(nwx, nwx, fmaf(nwy, nwy, nwz * nwz)));
            nx[j] = nwx * invn; ny[j] = nwy * invn; nz[j] = nwz * invn;
        }

        // plain vector stores (merge to full lines in L2)
        f32x4* tp = (f32x4*)(out) + 2 * g;
        tp[0] = (f32x4){tt[0], tt[1], tt[2], tt[3]};
        tp[1] = (f32x4){tt[4], tt[5], tt[6], tt[7]};

        f32x4* np_ = (f32x4*)(out + n) + 6 * g;
        np_[0] = (f32x4){nx[0], ny[0], nz[0], nx[1]};
        np_[1] = (f32x4){ny[1], nz[1], nx[2], ny[2]};
        np_[2] = (f32x4){nz[2], nx[3], ny[3], nz[3]};
        np_[3] = (f32x4){nx[4], ny[4], nz[4], nx[5]};
        np_[4] = (f32x4){ny[5], nz[5], nx[6], ny[6]};
        np_[5] = (f32x4){nz[6], nx[7], ny[7], nz[7]};

        f32x4* vp = (f32x4*)(out + 4 * n) + 2 * g;
        vp[0] = (f32x4){vd[0], vd[1], vd[2], vd[3]};
        vp[1] = (f32x4){vd[4], vd[5], vd[6], vd[7]};
    }

    // ---- scalar tail (n % 8) ----
    const int rem0 = ngroups8 << 3;
    for (int idx = rem0 + gid0; idx < n; idx += stride) {
        float dx = P[3 * idx + 0] - b[0], dy = P[3 * idx + 1] - b[1], dz = P[3 * idx + 2] - b[2];
        float Wx = V[3 * idx + 0], Wy = V[3 * idx + 1], Wz = V[3 * idx + 2];
        float plx = Ai[0][0] * dx + Ai[0][1] * dy + Ai[0][2] * dz;
        float ply = Ai[1][0] * dx + Ai[1][1] * dy + Ai[1][2] * dz;
        float plz = Ai[2][0] * dx + Ai[2][1] * dy + Ai[2][2] * dz;
        float vlx = Ai[0][0] * Wx + Ai[0][1] * Wy + Ai[0][2] * Wz;
        float vly = Ai[1][0] * Wx + Ai[1][1] * Wy + Ai[1][2] * Wz;
        float vlz = Ai[2][0] * Wx + Ai[2][1] * Wy + Ai[2][2] * Wz;
        float mx = plx - R;
        float bb = mx * vlx + ply * vly + plz * vlz;
        float aa = vlx * vlx + vly * vly + vlz * vlz;
        float c0 = mx * mx + ply * ply + plz * plz - RR;
        float D  = fmaxf(bb * bb - aa * c0, 0.0f);
        float q  = fsqrt(D) - bb;
        float t  = c0 * frcp(q);
        float py = __fadd_rn(ply, __fmul_rn(t, vly));
        float pz = __fadd_rn(plz, __fmul_rn(t, vlz));
        float r2 = __fadd_rn(__fmul_rn(py, py), __fmul_rn(pz, pz));
        float nlx = fmaf(t, vlx, mx);
        float nwx = nlx * Ai[0][0] + py * Ai[1][0] + pz * Ai[2][0];
        float nwy = nlx * Ai[0][1] + py * Ai[1][1] + pz * Ai[2][1];
        float nwz = nlx * Ai[0][2] + py * Ai[1][2] + pz * Ai[2][2];
        float invn = frsq(fmaf(nwx, nwx, fmaf(nwy, nwy, nwz * nwz)));
        out[idx] = t;
        out[n + 3 * idx + 0] = nwx * invn;
        out[n + 3 * idx + 1] = nwy * invn;
        out[n + 3 * idx + 2] = nwz * invn;
        out[4 * n + idx] = (sqrtf(r2) <= rlim) ? 1.0f : 0.0f;
    }
}

extern "C" void kernel_launch(void* const* d_in, const int* in_sizes, int n_in,
                              void* d_out, int out_size, void* d_ws, size_t ws_size,
                              hipStream_t stream) {
    const float* P  = (const float*)d_in[0];
    const float* V  = (const float*)d_in[1];
    const float* tf = (const float*)d_in[2];
    const float* diameter = (const float*)d_in[3];
    const float* C        = (const float*)d_in[4];
    const float* anchors  = (const float*)d_in[5];
    const float* scale    = (const float*)d_in[6];
    const unsigned char* normalize = (const unsigned char*)d_in[7];
    float* out = (float*)d_out;

    const int n = in_sizes[0] / 3;   // P is (N,3)

    const int block = 256;
    int blocks = ((n >> 3) + block - 1) / block;
    if (blocks > 4096) blocks = 4096;
    if (blocks < 1) blocks = 1;

    sphere_trace_kernel<<<blocks, block, 0, stream>>>(
        P, V, tf, diameter, C, anchors, scale, normalize, out, n);
}

// Round 8
// 38.259 us; speedup vs baseline: 3.2772x; 1.0591x over previous
//
#include <hip/hip_runtime.h>

#define TOL 1e-6f
#define EPSF 1e-12f

typedef float f32x4 __attribute__((ext_vector_type(4)));

__device__ __forceinline__ float frcp(float x)  { return __builtin_amdgcn_rcpf(x); }
__device__ __forceinline__ float frsq(float x)  { return __builtin_amdgcn_rsqf(x); }
__device__ __forceinline__ float fsqrt(float x) { return __builtin_amdgcn_sqrtf(x); }

// Closed form for the reference's 12 damped-Newton iterations: the sag surface
// x = C r^2/(1+sqrt(1-C^2 r^2)) is exactly the sphere (x-R)^2 + r^2 = R^2,
// R = 1/C; Newton converges to the near ray-sphere root to fp32 precision.
// t = c0/(sqrt(bb^2-aa*c0) - bb) (bb<0: cancellation-free). Normal direction
// = (px-R, py, pz) = positive multiple of the reference gradient.
// R5 lesson: no nontemporal stores (bypass L2 coalescing, 2.7x WRITE_SIZE).
// R6 lesson: 4 pts/thread > 8 pts/thread (TLP beats per-thread MLP; VGPR cap).
//
// ws layout (16 floats):
//  w0 = {Ai00, Ai01, Ai02, cx}   c = -Ai*b  (so pl = Ai*P + c)
//  w1 = {Ai10, Ai11, Ai12, cy}
//  w2 = {Ai20, Ai21, Ai22, cz}
//  w3 = {R, R*R, thr, 0}         thr: largest f32 with sqrt_rn(thr) <= rlim

__global__ void setup_kernel(const float* __restrict__ P,
                             const float* __restrict__ V,
                             const float* __restrict__ tf,
                             const float* __restrict__ diameter_p,
                             const float* __restrict__ C_p,
                             const float* __restrict__ anchors,
                             const float* __restrict__ scale_p,
                             float* __restrict__ out,
                             float* __restrict__ ws,
                             int n)
{
    const int tid = threadIdx.x;  // one block of 64 threads; all compute uniforms
    const float diameter = diameter_p[0];
    const float C        = C_p[0];
    const float scale    = scale_p[0];
    const float half = 0.5f * diameter;

    float a0 = anchors[0] * half;
    float a1 = anchors[1] * half;
    float r2a0 = a0 * a0;
    float r2a1 = a1 * a1;
    float s0 = fsqrt(fmaxf(1.0f - C * C * r2a0, EPSF));
    float s1 = fsqrt(fmaxf(1.0f - C * C * r2a1, EPSF));
    float e0 = C * r2a0 * frcp(1.0f + s0);
    float e1 = C * r2a1 * frcp(1.0f + s1);

    float A[3][3], b[3];
    #pragma unroll
    for (int i = 0; i < 3; ++i) {
        #pragma unroll
        for (int j = 0; j < 3; ++j) A[i][j] = tf[i * 4 + j] * scale;
        b[i] = tf[i * 4 + 3] - scale * e0 * tf[i * 4 + 0];
    }

    float ia = A[0][0], ib = A[0][1], ic = A[0][2];
    float id = A[1][0], ie = A[1][1], ifv = A[1][2];
    float ig = A[2][0], ih = A[2][1], ii = A[2][2];
    float det = ia * (ie * ii - ifv * ih) - ib * (id * ii - ifv * ig) + ic * (id * ih - ie * ig);
    float idet = frcp(det);
    float Ai[3][3];
    Ai[0][0] = (ie * ii - ifv * ih) * idet;
    Ai[0][1] = (ic * ih - ib * ii) * idet;
    Ai[0][2] = (ib * ifv - ic * ie) * idet;
    Ai[1][0] = (ifv * ig - id * ii) * idet;
    Ai[1][1] = (ia * ii - ic * ig) * idet;
    Ai[1][2] = (ic * id - ia * ifv) * idet;
    Ai[2][0] = (id * ih - ie * ig) * idet;
    Ai[2][1] = (ib * ig - ia * ih) * idet;
    Ai[2][2] = (ia * ie - ib * id) * idet;

    const float R    = 1.0f / C;
    const float RR   = R * R;
    const float rlim = __fadd_rn(half, TOL);

    // largest f32 thr with sqrt_rn(thr) <= rlim  (precise sqrtf; monotone)
    unsigned u = __float_as_uint(__fmul_rn(rlim, rlim));
    #pragma unroll 1
    while (sqrtf(__uint_as_float(u)) > rlim)  --u;
    #pragma unroll 1
    while (sqrtf(__uint_as_float(u + 1)) <= rlim) ++u;
    const float thr = __uint_as_float(u);

    if (tid == 0) {
        ws[ 0] = Ai[0][0]; ws[ 1] = Ai[0][1]; ws[ 2] = Ai[0][2];
        ws[ 3] = -(Ai[0][0] * b[0] + Ai[0][1] * b[1] + Ai[0][2] * b[2]);
        ws[ 4] = Ai[1][0]; ws[ 5] = Ai[1][1]; ws[ 6] = Ai[1][2];
        ws[ 7] = -(Ai[1][0] * b[0] + Ai[1][1] * b[1] + Ai[1][2] * b[2]);
        ws[ 8] = Ai[2][0]; ws[ 9] = Ai[2][1]; ws[10] = Ai[2][2];
        ws[11] = -(Ai[2][0] * b[0] + Ai[2][1] * b[1] + Ai[2][2] * b[2]);
        ws[12] = R; ws[13] = RR; ws[14] = thr; ws[15] = 0.0f;
    }

    // the two 4x4 output matrices
    if (tid < 32) {
        int m = tid & 15;
        int i = m >> 2, j = m & 3;
        float v;
        if (tid < 16) {
            v = (j < 3) ? tf[i * 4 + j] * scale
                        : tf[i * 4 + 3] - scale * e0 * tf[i * 4 + 0];
            out[5 * n + m] = v;
        } else {
            v = (j < 3) ? tf[i * 4 + j]
                        : tf[i * 4 + 3] + scale * (e1 - e0) * tf[i * 4 + 0];
            out[5 * n + 16 + m] = v;
        }
    }

    // scalar tail: points [n & ~3, n)
    const int rem = n & 3;
    if (tid >= 32 && tid < 32 + rem) {
        const int idx = (n & ~3) + (tid - 32);
        float Px = P[3 * idx + 0], Py = P[3 * idx + 1], Pz = P[3 * idx + 2];
        float Wx = V[3 * idx + 0], Wy = V[3 * idx + 1], Wz = V[3 * idx + 2];
        float cx = -(Ai[0][0] * b[0] + Ai[0][1] * b[1] + Ai[0][2] * b[2]);
        float cy = -(Ai[1][0] * b[0] + Ai[1][1] * b[1] + Ai[1][2] * b[2]);
        float cz = -(Ai[2][0] * b[0] + Ai[2][1] * b[1] + Ai[2][2] * b[2]);
        float plx = fmaf(Ai[0][0], Px, fmaf(Ai[0][1], Py, fmaf(Ai[0][2], Pz, cx)));
        float ply = fmaf(Ai[1][0], Px, fmaf(Ai[1][1], Py, fmaf(Ai[1][2], Pz, cy)));
        float plz = fmaf(Ai[2][0], Px, fmaf(Ai[2][1], Py, fmaf(Ai[2][2], Pz, cz)));
        float vlx = fmaf(Ai[0][0], Wx, fmaf(Ai[0][1], Wy, Ai[0][2] * Wz));
        float vly = fmaf(Ai[1][0], Wx, fmaf(Ai[1][1], Wy, Ai[1][2] * Wz));
        float vlz = fmaf(Ai[2][0], Wx, fmaf(Ai[2][1], Wy, Ai[2][2] * Wz));
        float mx = plx - R;
        float bb = mx * vlx + ply * vly + plz * vlz;
        float aa = vlx * vlx + vly * vly + vlz * vlz;
        float c0 = mx * mx + ply * ply + plz * plz - RR;
        float D  = fmaxf(bb * bb - aa * c0, 0.0f);
        float q  = fsqrt(D) - bb;
        float t  = c0 * frcp(q);
        float py = __fadd_rn(ply, __fmul_rn(t, vly));
        float pz = __fadd_rn(plz, __fmul_rn(t, vlz));
        float r2 = __fadd_rn(__fmul_rn(py, py), __fmul_rn(pz, pz));
        float nlx = fmaf(t, vlx, mx);
        float nwx = nlx * Ai[0][0] + py * Ai[1][0] + pz * Ai[2][0];
        float nwy = nlx * Ai[0][1] + py * Ai[1][1] + pz * Ai[2][1];
        float nwz = nlx * Ai[0][2] + py * Ai[1][2] + pz * Ai[2][2];
        float invn = frsq(fmaf(nwx, nwx, fmaf(nwy, nwy, nwz * nwz)));
        out[idx] = t;
        out[n + 3 * idx + 0] = nwx * invn;
        out[n + 3 * idx + 1] = nwy * invn;
        out[n + 3 * idx + 2] = nwz * invn;
        out[4 * n + idx] = (r2 <= thr) ? 1.0f : 0.0f;
    }
}

__global__ __launch_bounds__(256) void trace_kernel(
    const float* __restrict__ P,
    const float* __restrict__ V,
    const float* __restrict__ ws,
    float* __restrict__ out,
    int n)
{
    const int ngroups = n >> 2;
    const int g = blockIdx.x * 256 + threadIdx.x;
    if (g >= ngroups) return;

    // uniform constants: 4 vector loads, no dependent math
    const f32x4* __restrict__ W = (const f32x4*)ws;
    const f32x4 w0 = W[0], w1 = W[1], w2 = W[2], w3 = W[3];
    const float a00 = w0.x, a01 = w0.y, a02 = w0.z, cx = w0.w;
    const float a10 = w1.x, a11 = w1.y, a12 = w1.z, cy = w1.w;
    const float a20 = w2.x, a21 = w2.y, a22 = w2.z, cz = w2.w;
    const float R = w3.x, RR = w3.y, thr = w3.z;

    const f32x4* __restrict__ P4 = (const f32x4*)P;
    const f32x4* __restrict__ V4 = (const f32x4*)V;

    // 4 points = 12 floats = 3 f32x4 each of P and V
    f32x4 pa = P4[3 * g + 0];
    f32x4 pb = P4[3 * g + 1];
    f32x4 pc = P4[3 * g + 2];
    f32x4 va = V4[3 * g + 0];
    f32x4 vb = V4[3 * g + 1];
    f32x4 vc = V4[3 * g + 2];

    const float Px[4] = {pa.x, pa.w, pb.z, pc.y};
    const float Py[4] = {pa.y, pb.x, pb.w, pc.z};
    const float Pz[4] = {pa.z, pb.y, pc.x, pc.w};
    const float Wx[4] = {va.x, va.w, vb.z, vc.y};
    const float Wy[4] = {va.y, vb.x, vb.w, vc.z};
    const float Wz[4] = {va.z, vb.y, vc.x, vc.w};

    float tt[4], nx[4], ny[4], nz[4], vd[4];
    #pragma unroll
    for (int j = 0; j < 4; ++j) {
        float plx = fmaf(a00, Px[j], fmaf(a01, Py[j], fmaf(a02, Pz[j], cx)));
        float ply = fmaf(a10, Px[j], fmaf(a11, Py[j], fmaf(a12, Pz[j], cy)));
        float plz = fmaf(a20, Px[j], fmaf(a21, Py[j], fmaf(a22, Pz[j], cz)));
        float vlx = fmaf(a00, Wx[j], fmaf(a01, Wy[j], a02 * Wz[j]));
        float vly = fmaf(a10, Wx[j], fmaf(a11, Wy[j], a12 * Wz[j]));
        float vlz = fmaf(a20, Wx[j], fmaf(a21, Wy[j], a22 * Wz[j]));

        float mx = plx - R;
        float bb = fmaf(mx, vlx, fmaf(ply, vly, plz * vlz));
        float aa = fmaf(vlx, vlx, fmaf(vly, vly, vlz * vlz));
        float c0 = fmaf(mx, mx, fmaf(ply, ply, fmaf(plz, plz, -RR)));
        float D  = fmaxf(fmaf(bb, bb, -aa * c0), 0.0f);
        float q  = fsqrt(D) - bb;
        float t  = c0 * frcp(q);
        tt[j] = t;

        // valid: r2 ops mirror numpy (mul/add, no fma); thr compare ==
        // sqrt_rn(r2) <= rlim bit-exactly (thr from setup bit-search)
        float py = __fadd_rn(ply, __fmul_rn(t, vly));
        float pz = __fadd_rn(plz, __fmul_rn(t, vlz));
        float r2 = __fadd_rn(__fmul_rn(py, py), __fmul_rn(pz, pz));
        vd[j] = (r2 <= thr) ? 1.0f : 0.0f;

        float nlx = fmaf(t, vlx, mx);
        float nwx = fmaf(nlx, a00, fmaf(py, a10, pz * a20));
        float nwy = fmaf(nlx, a01, fmaf(py, a11, pz * a21));
        float nwz = fmaf(nlx, a02, fmaf(py, a12, pz * a22));
        float invn = frsq(fmaf(nwx, nwx, fmaf(nwy, nwy, nwz * nwz)));
        nx[j] = nwx * invn; ny[j] = nwy * invn; nz[j] = nwz * invn;
    }

    ((f32x4*)out)[g] = (f32x4){tt[0], tt[1], tt[2], tt[3]};

    f32x4* np_ = (f32x4*)(out + n) + 3 * g;
    np_[0] = (f32x4){nx[0], ny[0], nz[0], nx[1]};
    np_[1] = (f32x4){ny[1], nz[1], nx[2], ny[2]};
    np_[2] = (f32x4){nz[2], nx[3], ny[3], nz[3]};

    ((f32x4*)(out + 4 * n))[g] = (f32x4){vd[0], vd[1], vd[2], vd[3]};
}

extern "C" void kernel_launch(void* const* d_in, const int* in_sizes, int n_in,
                              void* d_out, int out_size, void* d_ws, size_t ws_size,
                              hipStream_t stream) {
    const float* P  = (const float*)d_in[0];
    const float* V  = (const float*)d_in[1];
    const float* tf = (const float*)d_in[2];
    const float* diameter = (const float*)d_in[3];
    const float* C        = (const float*)d_in[4];
    const float* anchors  = (const float*)d_in[5];
    const float* scale    = (const float*)d_in[6];
    float* out = (float*)d_out;
    float* ws  = (float*)d_ws;

    const int n = in_sizes[0] / 3;   // P is (N,3)

    setup_kernel<<<1, 64, 0, stream>>>(P, V, tf, diameter, C, anchors, scale, out, ws, n);

    const int ngroups = n >> 2;
    const int blocks = (ngroups + 255) / 256;
    trace_kernel<<<blocks, 256, 0, stream>>>(P, V, ws, out, n);
}

// Round 9
// 34.456 us; speedup vs baseline: 3.6389x; 1.1104x over previous
//
#include <hip/hip_runtime.h>

#define TOL 1e-6f
#define EPSF 1e-12f

typedef float f32x4 __attribute__((ext_vector_type(4)));

__device__ __forceinline__ float frcp(float x)  { return __builtin_amdgcn_rcpf(x); }
__device__ __forceinline__ float frsq(float x)  { return __builtin_amdgcn_rsqf(x); }
__device__ __forceinline__ float fsqrt(float x) { return __builtin_amdgcn_sqrtf(x); }

// Closed form for the reference's 12 damped-Newton iterations: the sag surface
// x = C r^2/(1+sqrt(1-C^2 r^2)) is exactly the sphere (x-R)^2 + r^2 = R^2,
// R = 1/C; Newton converges to the near ray-sphere root to fp32 precision.
// t = c0/(sqrt(bb^2-aa*c0) - bb) (bb<0: cancellation-free). Normal direction
// = (px-R, py, pz) = positive multiple of the reference gradient.
// R5: no nontemporal stores (bypass L2 coalescing, 2.7x WRITE_SIZE, 3.7x time).
// R6: 4 pts/thread > 8 (TLP beats per-thread MLP; VGPR cap).
// R8: separate setup kernel costs ~4us serialized launch; VALU cut 20->9% did
//     NOT move time -> kernel is L3/fabric-rate bound, keep setup inline.

__global__ __launch_bounds__(256) void sphere_trace_kernel(
    const float* __restrict__ P,
    const float* __restrict__ V,
    const float* __restrict__ tf,
    const float* __restrict__ diameter_p,
    const float* __restrict__ C_p,
    const float* __restrict__ anchors,
    const float* __restrict__ scale_p,
    const unsigned char* __restrict__ normalize_p,
    float* __restrict__ out,
    int n)
{
    // ---- uniform scalar setup (broadcast loads, cached; VALU is not the
    //      limiter: 9-20% across rounds) ----
    const float diameter = diameter_p[0];
    const float C        = C_p[0];
    const float scale    = scale_p[0];
    const float half = 0.5f * diameter;

    float a0 = anchors[0] * half;
    float a1 = anchors[1] * half;
    float r2a0 = a0 * a0;
    float r2a1 = a1 * a1;
    float s0 = fsqrt(fmaxf(1.0f - C * C * r2a0, EPSF));
    float s1 = fsqrt(fmaxf(1.0f - C * C * r2a1, EPSF));
    float e0 = C * r2a0 * frcp(1.0f + s0);
    float e1 = C * r2a1 * frcp(1.0f + s1);

    float A[3][3], b[3];
    #pragma unroll
    for (int i = 0; i < 3; ++i) {
        #pragma unroll
        for (int j = 0; j < 3; ++j) A[i][j] = tf[i * 4 + j] * scale;
        b[i] = tf[i * 4 + 3] - scale * e0 * tf[i * 4 + 0];
    }

    float ia = A[0][0], ib = A[0][1], ic = A[0][2];
    float id = A[1][0], ie = A[1][1], ifv = A[1][2];
    float ig = A[2][0], ih = A[2][1], ii = A[2][2];
    float det = ia * (ie * ii - ifv * ih) - ib * (id * ii - ifv * ig) + ic * (id * ih - ie * ig);
    float idet = frcp(det);
    float a00 = (ie * ii - ifv * ih) * idet;
    float a01 = (ic * ih - ib * ii) * idet;
    float a02 = (ib * ifv - ic * ie) * idet;
    float a10 = (ifv * ig - id * ii) * idet;
    float a11 = (ia * ii - ic * ig) * idet;
    float a12 = (ic * id - ia * ifv) * idet;
    float a20 = (id * ih - ie * ig) * idet;
    float a21 = (ib * ig - ia * ih) * idet;
    float a22 = (ia * ie - ib * id) * idet;

    const float cx = -(a00 * b[0] + a01 * b[1] + a02 * b[2]);
    const float cy = -(a10 * b[0] + a11 * b[1] + a12 * b[2]);
    const float cz = -(a20 * b[0] + a21 * b[1] + a22 * b[2]);

    const float R    = 1.0f / C;
    const float RR   = R * R;
    const float rlim = __fadd_rn(half, TOL);

    // largest f32 thr with sqrt_rn(thr) <= rlim (monotone bit-search, ~2 iters;
    // makes valid = (r2 <= thr) bit-identical to np.sqrt(r2) <= rlim)
    unsigned u = __float_as_uint(__fmul_rn(rlim, rlim));
    #pragma unroll 1
    while (sqrtf(__uint_as_float(u)) > rlim)  --u;
    #pragma unroll 1
    while (sqrtf(__uint_as_float(u + 1)) <= rlim) ++u;
    const float thr = __uint_as_float(u);

    const int gid0 = blockIdx.x * blockDim.x + threadIdx.x;

    // ---- the two 4x4 matrices (32 floats) ----
    if (gid0 < 32) {
        int m = gid0 & 15;
        int i = m >> 2, j = m & 3;
        float v;
        if (gid0 < 16) {
            v = (j < 3) ? tf[i * 4 + j] * scale
                        : tf[i * 4 + 3] - scale * e0 * tf[i * 4 + 0];
            out[5 * n + m] = v;
        } else {
            v = (j < 3) ? tf[i * 4 + j]
                        : tf[i * 4 + 3] + scale * (e1 - e0) * tf[i * 4 + 0];
            out[5 * n + 16 + m] = v;
        }
    }

    // ---- scalar tail (n % 4), threads 32..35 of block 0 ----
    const int rem = n & 3;
    if (gid0 >= 32 && gid0 < 32 + rem) {
        const int idx = (n & ~3) + (gid0 - 32);
        float Px = P[3 * idx + 0], Py = P[3 * idx + 1], Pz = P[3 * idx + 2];
        float Wx = V[3 * idx + 0], Wy = V[3 * idx + 1], Wz = V[3 * idx + 2];
        float plx = fmaf(a00, Px, fmaf(a01, Py, fmaf(a02, Pz, cx)));
        float ply = fmaf(a10, Px, fmaf(a11, Py, fmaf(a12, Pz, cy)));
        float plz = fmaf(a20, Px, fmaf(a21, Py, fmaf(a22, Pz, cz)));
        float vlx = fmaf(a00, Wx, fmaf(a01, Wy, a02 * Wz));
        float vly = fmaf(a10, Wx, fmaf(a11, Wy, a12 * Wz));
        float vlz = fmaf(a20, Wx, fmaf(a21, Wy, a22 * Wz));
        float mx = plx - R;
        float bb = fmaf(mx, vlx, fmaf(ply, vly, plz * vlz));
        float aa = fmaf(vlx, vlx, fmaf(vly, vly, vlz * vlz));
        float c0 = fmaf(mx, mx, fmaf(ply, ply, fmaf(plz, plz, -RR)));
        float D  = fmaxf(fmaf(bb, bb, -aa * c0), 0.0f);
        float q  = fsqrt(D) - bb;
        float t  = c0 * frcp(q);
        float py = __fadd_rn(ply, __fmul_rn(t, vly));
        float pz = __fadd_rn(plz, __fmul_rn(t, vlz));
        float r2 = __fadd_rn(__fmul_rn(py, py), __fmul_rn(pz, pz));
        float nlx = fmaf(t, vlx, mx);
        float nwx = fmaf(nlx, a00, fmaf(py, a10, pz * a20));
        float nwy = fmaf(nlx, a01, fmaf(py, a11, pz * a21));
        float nwz = fmaf(nlx, a02, fmaf(py, a12, pz * a22));
        float invn = frsq(fmaf(nwx, nwx, fmaf(nwy, nwy, nwz * nwz)));
        out[idx] = t;
        out[n + 3 * idx + 0] = nwx * invn;
        out[n + 3 * idx + 1] = nwy * invn;
        out[n + 3 * idx + 2] = nwz * invn;
        out[4 * n + idx] = (r2 <= thr) ? 1.0f : 0.0f;
    }

    // ---- main: 4 points per thread, exact grid ----
    const int ngroups = n >> 2;
    const int g = gid0;
    if (g >= ngroups) return;

    const f32x4* __restrict__ P4 = (const f32x4*)P;
    const f32x4* __restrict__ V4 = (const f32x4*)V;

    f32x4 pa = P4[3 * g + 0];
    f32x4 pb = P4[3 * g + 1];
    f32x4 pc = P4[3 * g + 2];
    f32x4 va = V4[3 * g + 0];
    f32x4 vb = V4[3 * g + 1];
    f32x4 vc = V4[3 * g + 2];

    const float Px[4] = {pa.x, pa.w, pb.z, pc.y};
    const float Py[4] = {pa.y, pb.x, pb.w, pc.z};
    const float Pz[4] = {pa.z, pb.y, pc.x, pc.w};
    const float Wx[4] = {va.x, va.w, vb.z, vc.y};
    const float Wy[4] = {va.y, vb.x, vb.w, vc.z};
    const float Wz[4] = {va.z, vb.y, vc.x, vc.w};

    float tt[4], nx[4], ny[4], nz[4], vd[4];
    #pragma unroll
    for (int j = 0; j < 4; ++j) {
        float plx = fmaf(a00, Px[j], fmaf(a01, Py[j], fmaf(a02, Pz[j], cx)));
        float ply = fmaf(a10, Px[j], fmaf(a11, Py[j], fmaf(a12, Pz[j], cy)));
        float plz = fmaf(a20, Px[j], fmaf(a21, Py[j], fmaf(a22, Pz[j], cz)));
        float vlx = fmaf(a00, Wx[j], fmaf(a01, Wy[j], a02 * Wz[j]));
        float vly = fmaf(a10, Wx[j], fmaf(a11, Wy[j], a12 * Wz[j]));
        float vlz = fmaf(a20, Wx[j], fmaf(a21, Wy[j], a22 * Wz[j]));

        float mx = plx - R;
        float bb = fmaf(mx, vlx, fmaf(ply, vly, plz * vlz));
        float aa = fmaf(vlx, vlx, fmaf(vly, vly, vlz * vlz));
        float c0 = fmaf(mx, mx, fmaf(ply, ply, fmaf(plz, plz, -RR)));
        float D  = fmaxf(fmaf(bb, bb, -aa * c0), 0.0f);
        float q  = fsqrt(D) - bb;
        float t  = c0 * frcp(q);
        tt[j] = t;

        float py = __fadd_rn(ply, __fmul_rn(t, vly));
        float pz = __fadd_rn(plz, __fmul_rn(t, vlz));
        float r2 = __fadd_rn(__fmul_rn(py, py), __fmul_rn(pz, pz));
        vd[j] = (r2 <= thr) ? 1.0f : 0.0f;

        float nlx = fmaf(t, vlx, mx);
        float nwx = fmaf(nlx, a00, fmaf(py, a10, pz * a20));
        float nwy = fmaf(nlx, a01, fmaf(py, a11, pz * a21));
        float nwz = fmaf(nlx, a02, fmaf(py, a12, pz * a22));
        float invn = frsq(fmaf(nwx, nwx, fmaf(nwy, nwy, nwz * nwz)));
        nx[j] = nwx * invn; ny[j] = nwy * invn; nz[j] = nwz * invn;
    }

    ((f32x4*)out)[g] = (f32x4){tt[0], tt[1], tt[2], tt[3]};

    f32x4* np_ = (f32x4*)(out + n) + 3 * g;
    np_[0] = (f32x4){nx[0], ny[0], nz[0], nx[1]};
    np_[1] = (f32x4){ny[1], nz[1], nx[2], ny[2]};
    np_[2] = (f32x4){nz[2], nx[3], ny[3], nz[3]};

    ((f32x4*)(out + 4 * n))[g] = (f32x4){vd[0], vd[1], vd[2], vd[3]};
}

extern "C" void kernel_launch(void* const* d_in, const int* in_sizes, int n_in,
                              void* d_out, int out_size, void* d_ws, size_t ws_size,
                              hipStream_t stream) {
    const float* P  = (const float*)d_in[0];
    const float* V  = (const float*)d_in[1];
    const float* tf = (const float*)d_in[2];
    const float* diameter = (const float*)d_in[3];
    const float* C        = (const float*)d_in[4];
    const float* anchors  = (const float*)d_in[5];
    const float* scale    = (const float*)d_in[6];
    const unsigned char* normalize = (const unsigned char*)d_in[7];
    float* out = (float*)d_out;

    const int n = in_sizes[0] / 3;   // P is (N,3)

    const int ngroups = n >> 2;
    const int blocks = (ngroups + 255) / 256;   // exact grid, no stride loop

    sphere_trace_kernel<<<blocks, 256, 0, stream>>>(
        P, V, tf, diameter, C, anchors, scale, normalize, out, n);
}